// Round 8
// baseline (454.589 us; speedup 1.0000x reference)
//
#include <hip/hip_runtime.h>

typedef unsigned short u16;
typedef __bf16 bf16x8 __attribute__((ext_vector_type(8)));
typedef float f32x16 __attribute__((ext_vector_type(16)));

union B8 { bf16x8 v; u16 s[8]; unsigned u[4]; uint4 u4; };

__device__ __forceinline__ unsigned cvtpk(float a, float b) {
    unsigned r;
    asm("v_cvt_pk_bf16_f32 %0, %1, %2" : "=v"(r) : "v"(a), "v"(b));
    return r;
}
__device__ __forceinline__ float ex2(float x) { return __builtin_amdgcn_exp2f(x); }
__device__ __forceinline__ void swap32(unsigned &a, unsigned &b) {
    asm("v_permlane32_swap_b32 %0, %1" : "+v"(a), "+v"(b));
}
__device__ __forceinline__ B8 load_w8(const float* __restrict__ p, float s) {
    float4 lo = ((const float4*)p)[0];
    float4 hi = ((const float4*)p)[1];
    B8 r;
    r.u[0] = cvtpk(lo.x * s, lo.y * s);
    r.u[1] = cvtpk(lo.z * s, lo.w * s);
    r.u[2] = cvtpk(hi.x * s, hi.y * s);
    r.u[3] = cvtpk(hi.z * s, hi.w * s);
    return r;
}
__device__ __forceinline__ f32x16 mfma32(const B8 a, const B8 b, f32x16 c) {
    return __builtin_amdgcn_mfma_f32_32x32x16_bf16(a.v, b.v, c, 0, 0, 0);
}
// K LDS: [512 tok][32 ck] u16, 4x16B slots per row XOR-swizzled by (tok>>1)&3
__device__ __forceinline__ int kidx(int row, int sl) {
    return row * 32 + (((sl ^ (row >> 1)) & 3) << 3);
}
// V LDS: [64 cv][256 tok-half] u16, 32 slots of 8, slot ^= SWZV(cv)
#define SWZV(cv) (((cv) ^ ((cv) >> 3)) & 7)
// D-regs (rows (r&3)+8*(r>>2)+4*h5) -> two B-fragments (k-chunks of 16) via cvtpk+permlane
__device__ __forceinline__ void build_b(const float* p, B8& b0, B8& b1) {
    unsigned c0 = cvtpk(p[0], p[1]),   c1 = cvtpk(p[2], p[3]);
    unsigned c2 = cvtpk(p[4], p[5]),   c3 = cvtpk(p[6], p[7]);
    unsigned c4 = cvtpk(p[8], p[9]),   c5 = cvtpk(p[10], p[11]);
    unsigned c6 = cvtpk(p[12], p[13]), c7 = cvtpk(p[14], p[15]);
    swap32(c0, c2); swap32(c1, c3); swap32(c4, c6); swap32(c5, c7);
    b0.u[0] = c0; b0.u[1] = c1; b0.u[2] = c2; b0.u[3] = c3;
    b1.u[0] = c4; b1.u[1] = c5; b1.u[2] = c6; b1.u[3] = c7;
}

#define WSC 0.50506330f   // sqrt(log2(e)/sqrt(32)) folded into K weights

// LDS (u16 idx): K [512][32] swz @0 (32KB) | V-half [64][256] swz @16384 (32KB) | X [128][64] swz @32768 (16KB)
// total 40960 u16 = 81920 B = exactly 80KB -> 2 blocks/CU.  Epilogue fout overlay: 8 waves x 8KB @0.
#define VOFF 16384
#define XOFF 32768

__global__ __launch_bounds__(512, 4)
void psab_fused(const float* __restrict__ x,
                const float* __restrict__ wk, const float* __restrict__ bk,
                const float* __restrict__ wv, const float* __restrict__ bv,
                const float* __restrict__ wo, const float* __restrict__ bo,
                float* __restrict__ out)
{
    __shared__ __align__(16) u16 smem[40960];
    const int t    = threadIdx.x;
    const int lane = t & 63;
    const int wid  = t >> 6;        // 8 waves
    const int cl   = lane & 31;
    const int h5   = lane >> 5;

    const int bid = blockIdx.x;
    const int n   = (bid & 7) * 64 + (bid >> 3);   // XCD-bijective swizzle
    const int sh = n >> 6, sw = (n >> 3) & 7, sd = n & 7;
    const size_t base_vox = (size_t)(sh * 8) * 4096 + (size_t)(sw * 8) * 64 + (size_t)(sd * 8);

    const f32x16 z16 = {0,0,0,0,0,0,0,0,0,0,0,0,0,0,0,0};

    // ---- per-wave proj weights: waves 0-3 = K, waves 4-7 = V(half A) ----
    B8 wpA[4], wvB[2][4];
    float bkv[16];
    float vb0 = 0.f, vb1 = 0.f;
    if (wid < 4) {
#pragma unroll
        for (int kc = 0; kc < 4; ++kc)
            wpA[kc] = load_w8(wk + cl * 64 + kc * 16 + h5 * 8, WSC);
#pragma unroll
        for (int r = 0; r < 16; ++r)
            bkv[r] = bk[(r & 3) + 8 * (r >> 2) + 4 * h5] * WSC;
    } else {
#pragma unroll
        for (int nb = 0; nb < 2; ++nb)
#pragma unroll
            for (int kc = 0; kc < 4; ++kc)
                wvB[nb][kc] = load_w8(wv + (nb * 32 + cl) * 64 + kc * 16 + h5 * 8, 1.0f);
        vb0 = bv[cl]; vb1 = bv[32 + cl];
    }

    // ---- X staging: chunk = 128 tok (2 hb x 8 wb x 8 db); thread: ch = lane-ish, row-slot = wid ----
    const int ch  = t & 63;
    const int rsl = t >> 6;          // 0..7 = wb
    float4 L4[2], H4[2];
#define LDX(cc)                                                                               \
    _Pragma("unroll")                                                                         \
    for (int i = 0; i < 2; ++i) {                                                             \
        const float* gp = x + (size_t)ch * 262144 + base_vox                                  \
                        + ((cc) * 2 + i) * 4096 + rsl * 64;                                   \
        L4[i] = ((const float4*)gp)[0];                                                       \
        H4[i] = ((const float4*)gp)[1];                                                       \
    }
    // X[ltok][ch]: slot = (ch>>3) ^ (ltok&7) = (ch>>3) ^ j
#define STX()                                                                                 \
    _Pragma("unroll")                                                                         \
    for (int i = 0; i < 2; ++i) {                                                             \
        const int rr = i * 8 + rsl;                                                           \
        unsigned a0 = cvtpk(L4[i].x, L4[i].y), a1 = cvtpk(L4[i].z, L4[i].w);                  \
        unsigned a2 = cvtpk(H4[i].x, H4[i].y), a3 = cvtpk(H4[i].z, H4[i].w);                  \
        const u16 vals[8] = { (u16)a0, (u16)(a0 >> 16), (u16)a1, (u16)(a1 >> 16),             \
                              (u16)a2, (u16)(a2 >> 16), (u16)a3, (u16)(a3 >> 16) };           \
        _Pragma("unroll")                                                                     \
        for (int j = 0; j < 8; ++j)                                                           \
            smem[XOFF + (rr * 8 + j) * 64 + (((ch >> 3) ^ j) << 3) + (ch & 7)] = vals[j];     \
    }
    // ax fragments for chunk-local 32-token group gL
#define AXLOAD(gL)                                                                            \
    {                                                                                         \
        const int ltokL = (gL) * 32 + cl;                                                     \
        _Pragma("unroll")                                                                     \
        for (int kc = 0; kc < 4; ++kc)                                                        \
            ax[kc].u4 = *(const uint4*)&smem[XOFF + ltokL * 64 +                              \
                                             (((2 * kc + h5) ^ (cl & 7)) << 3)];              \
    }
    // V store: group base (local-in-half) VBASE, weights W, bias pair
#define VSTORE(VBASE, W, VB0, VB1)                                                            \
    _Pragma("unroll")                                                                         \
    for (int nb = 0; nb < NBN; ++nb) {                                                        \
        f32x16 vd = mfma32(ax[0], W[nb][0], z16);                                             \
        vd = mfma32(ax[1], W[nb][1], vd);                                                     \
        vd = mfma32(ax[2], W[nb][2], vd);                                                     \
        vd = mfma32(ax[3], W[nb][3], vd);                                                     \
        const int cv = (NB0 + nb) * 32 + cl;                                                  \
        const float vb = (NB0 + nb) ? (VB1) : (VB0);                                          \
        _Pragma("unroll")                                                                     \
        for (int rq = 0; rq < 4; ++rq) {                                                      \
            uint2 pk;                                                                         \
            pk.x = cvtpk(vd[rq * 4 + 0] + vb, vd[rq * 4 + 1] + vb);                           \
            pk.y = cvtpk(vd[rq * 4 + 2] + vb, vd[rq * 4 + 3] + vb);                           \
            const int off = (VBASE) + rq * 8 + 4 * h5;                                        \
            *(uint2*)&smem[VOFF + cv * 256 + (((off >> 3) ^ SWZV(cv)) << 3) + (off & 7)] = pk;\
        }                                                                                     \
    }

    // ---- proj phase: 4 X chunks; waves 0-3 K, waves 4-7 V (chunks 0,1 only) ----
    LDX(0)
#pragma unroll
    for (int cc = 0; cc < 4; ++cc) {
        if (cc > 0) __syncthreads();          // chunk cc-1 X readers done
        STX()
        __syncthreads();                      // X cc visible
        if (cc < 3) { LDX(cc + 1) }           // prefetch next chunk under MFMAs
        B8 ax[4];
        if (wid < 4) {
            AXLOAD(wid)
            f32x16 kd = mfma32(wpA[0], ax[0], z16);
            kd = mfma32(wpA[1], ax[1], kd);
            kd = mfma32(wpA[2], ax[2], kd);
            kd = mfma32(wpA[3], ax[3], kd);
            const int trow = cc * 128 + wid * 32 + cl;
#pragma unroll
            for (int g = 0; g < 4; ++g) {
                uint2 pk;
                pk.x = cvtpk(kd[4 * g + 0] + bkv[4 * g + 0], kd[4 * g + 1] + bkv[4 * g + 1]);
                pk.y = cvtpk(kd[4 * g + 2] + bkv[4 * g + 2], kd[4 * g + 3] + bkv[4 * g + 3]);
                *(uint2*)&smem[kidx(trow, g) + 4 * h5] = pk;
            }
        } else if (cc < 2) {
            AXLOAD(wid - 4)
#define NBN 2
#define NB0 0
            VSTORE(cc * 128 + (wid - 4) * 32, wvB, vb0, vb1)
#undef NBN
#undef NB0
        }
    }
    __syncthreads();                          // K full + V half-A ready

    // ---- attention setup: wave owns q = wid*64 + qb*32 + cl ----
    B8 qB[2][2];
#pragma unroll
    for (int qb = 0; qb < 2; ++qb)
#pragma unroll
        for (int kc = 0; kc < 2; ++kc)
            qB[qb][kc].u4 = *(const uint4*)&smem[kidx(wid * 64 + qb * 32 + cl, 2 * kc + h5)];

    f32x16 ctx00 = z16, ctx01 = z16, ctx10 = z16, ctx11 = z16;   // ctx[qb][cvb]
    float ls0 = 0.f, ls1 = 0.f;

#define SM(qb, sv, c0, c1)                                                                    \
    {                                                                                         \
        float p[16];                                                                          \
        _Pragma("unroll")                                                                     \
        for (int i2 = 0; i2 < 16; ++i2) p[i2] = ex2(sv[i2]);                                  \
        ls##qb += (((p[0]+p[1])+(p[2]+p[3]))+((p[4]+p[5])+(p[6]+p[7])))                       \
                + (((p[8]+p[9])+(p[10]+p[11]))+((p[12]+p[13])+(p[14]+p[15])));                \
        B8 pb0, pb1;                                                                          \
        build_b(p, pb0, pb1);                                                                 \
        __builtin_amdgcn_s_setprio(1);                                                        \
        c0 = mfma32(va00, pb0, c0);                                                           \
        c0 = mfma32(va01, pb1, c0);                                                           \
        c1 = mfma32(va10, pb0, c1);                                                           \
        c1 = mfma32(va11, pb1, c1);                                                           \
        __builtin_amdgcn_s_setprio(0);                                                        \
    }

#define ATTN_PASS(CI0, CI1, MOFF)                                                             \
    _Pragma("unroll 2")                                                                       \
    for (int ci = (CI0); ci < (CI1); ++ci) {                                                  \
        const int m0 = ci * 32;                                                               \
        const int vs = ((m0 - (MOFF)) >> 3) + h5;                                             \
        B8 kA0, kA1, va00, va01, va10, va11;                                                  \
        kA0.u4  = *(const uint4*)&smem[kidx(m0 + cl, h5)];                                    \
        kA1.u4  = *(const uint4*)&smem[kidx(m0 + cl, 2 + h5)];                                \
        va00.u4 = *(const uint4*)&smem[VOFF + cl * 256 + ((vs ^ SWZV(cl)) << 3)];             \
        va01.u4 = *(const uint4*)&smem[VOFF + cl * 256 + (((vs + 2) ^ SWZV(cl)) << 3)];       \
        va10.u4 = *(const uint4*)&smem[VOFF + (32 + cl) * 256 + ((vs ^ SWZV(32 + cl)) << 3)]; \
        va11.u4 = *(const uint4*)&smem[VOFF + (32 + cl) * 256 +                               \
                                       (((vs + 2) ^ SWZV(32 + cl)) << 3)];                    \
        __builtin_amdgcn_s_setprio(1);                                                        \
        f32x16 s0 = mfma32(kA0, qB[0][0], z16); s0 = mfma32(kA1, qB[0][1], s0);               \
        f32x16 s1 = mfma32(kA0, qB[1][0], z16); s1 = mfma32(kA1, qB[1][1], s1);               \
        __builtin_amdgcn_s_setprio(0);                                                        \
        SM(0, s0, ctx00, ctx01)                                                               \
        SM(1, s1, ctx10, ctx11)                                                               \
    }

    ATTN_PASS(0, 8, 0)
    __syncthreads();                          // half-A V reads done; X region free

    // ---- V half-B: all 8 waves; wave -> (group wid>>1, nb wid&1) ----
    B8 wvw[4];
    const int nbw = wid & 1;
#pragma unroll
    for (int kc = 0; kc < 4; ++kc)
        wvw[kc] = load_w8(wv + (nbw * 32 + cl) * 64 + kc * 16 + h5 * 8, 1.0f);
    const float vbw = bv[nbw * 32 + cl];

    LDX(2)
    STX()
    __syncthreads();                          // X2 visible
    LDX(3)
    {
        B8 ax[4];
        AXLOAD(wid >> 1)
        f32x16 vd = mfma32(ax[0], wvw[0], z16);
        vd = mfma32(ax[1], wvw[1], vd);
        vd = mfma32(ax[2], wvw[2], vd);
        vd = mfma32(ax[3], wvw[3], vd);
        const int cv = nbw * 32 + cl;
        const int vbase = (wid >> 1) * 32;    // local-in-half-B, chunk2 -> 0..127
#pragma unroll
        for (int rq = 0; rq < 4; ++rq) {
            uint2 pk;
            pk.x = cvtpk(vd[rq * 4 + 0] + vbw, vd[rq * 4 + 1] + vbw);
            pk.y = cvtpk(vd[rq * 4 + 2] + vbw, vd[rq * 4 + 3] + vbw);
            const int off = vbase + rq * 8 + 4 * h5;
            *(uint2*)&smem[VOFF + cv * 256 + (((off >> 3) ^ SWZV(cv)) << 3) + (off & 7)] = pk;
        }
    }
    __syncthreads();                          // X2 readers done
    STX()
    __syncthreads();                          // X3 visible
    {
        B8 ax[4];
        AXLOAD(wid >> 1)
        f32x16 vd = mfma32(ax[0], wvw[0], z16);
        vd = mfma32(ax[1], wvw[1], vd);
        vd = mfma32(ax[2], wvw[2], vd);
        vd = mfma32(ax[3], wvw[3], vd);
        const int cv = nbw * 32 + cl;
        const int vbase = 128 + (wid >> 1) * 32;   // chunk3 -> 128..255
#pragma unroll
        for (int rq = 0; rq < 4; ++rq) {
            uint2 pk;
            pk.x = cvtpk(vd[rq * 4 + 0] + vbw, vd[rq * 4 + 1] + vbw);
            pk.y = cvtpk(vd[rq * 4 + 2] + vbw, vd[rq * 4 + 3] + vbw);
            const int off = vbase + rq * 8 + 4 * h5;
            *(uint2*)&smem[VOFF + cv * 256 + (((off >> 3) ^ SWZV(cv)) << 3) + (off & 7)] = pk;
        }
    }
    __syncthreads();                          // V half-B ready

    ATTN_PASS(8, 16, 256)

    ls0 += __shfl_xor(ls0, 32);
    ls1 += __shfl_xor(ls1, 32);
    const float inv0 = 1.0f / ls0, inv1 = 1.0f / ls1;

    // out-proj A-frags + ctx -> B-frags (registers only)
    B8 aw[2][4];
#pragma unroll
    for (int cob = 0; cob < 2; ++cob)
#pragma unroll
        for (int kc = 0; kc < 4; ++kc)
            aw[cob][kc] = load_w8(wo + (cob * 32 + cl) * 64 + kc * 16 + h5 * 8, 1.0f);

    float pn[16];
    B8 cq0[4], cq1[4];
#pragma unroll
    for (int i = 0; i < 16; ++i) pn[i] = ctx00[i] * inv0;
    build_b(pn, cq0[0], cq0[1]);
#pragma unroll
    for (int i = 0; i < 16; ++i) pn[i] = ctx01[i] * inv0;
    build_b(pn, cq0[2], cq0[3]);
#pragma unroll
    for (int i = 0; i < 16; ++i) pn[i] = ctx10[i] * inv1;
    build_b(pn, cq1[0], cq1[1]);
#pragma unroll
    for (int i = 0; i < 16; ++i) pn[i] = ctx11[i] * inv1;
    build_b(pn, cq1[2], cq1[3]);

    __syncthreads();                          // all K/V LDS reads done; fout overlay safe

    float* fout = (float*)((char*)smem + wid * 8192);   // [64 co][32 q] f32, col ^ ((co&7)<<2)
    const int ql4  = (lane & 7) * 4;
    const int xorv = (lane >> 3) << 2;
    const float invq[2] = { inv0, inv1 };     // (unused; kept for clarity)
    (void)invq;

#pragma unroll
    for (int qb = 0; qb < 2; ++qb) {
#pragma unroll
        for (int cob = 0; cob < 2; ++cob) {
            f32x16 od = qb == 0 ? mfma32(aw[cob][0], cq0[0], z16)
                                : mfma32(aw[cob][0], cq1[0], z16);
            if (qb == 0) {
                od = mfma32(aw[cob][1], cq0[1], od);
                od = mfma32(aw[cob][2], cq0[2], od);
                od = mfma32(aw[cob][3], cq0[3], od);
            } else {
                od = mfma32(aw[cob][1], cq1[1], od);
                od = mfma32(aw[cob][2], cq1[2], od);
                od = mfma32(aw[cob][3], cq1[3], od);
            }
#pragma unroll
            for (int r = 0; r < 16; ++r) {
                const int row = cob * 32 + (r & 3) + 8 * (r >> 2) + 4 * h5;
                fout[row * 32 + (cl ^ ((row & 7) << 2))] = od[r];
            }
        }
        // store: tok = wid*64 + qb*32 + ql4..+3; per instruction 8 co x 8 lanes
        float* outw = out + base_vox + (size_t)wid * 4096
                    + (qb * 4 + (ql4 >> 3)) * 64 + (ql4 & 7);
#pragma unroll
        for (int it = 0; it < 8; ++it) {
            const int co = it * 8 + (lane >> 3);
            float4 v4 = *(const float4*)&fout[co * 32 + (ql4 ^ xorv)];
            const float bco = bo[co];
            v4.x += bco; v4.y += bco; v4.z += bco; v4.w += bco;
            *(float4*)&outw[(size_t)co * 262144] = v4;
        }
    }
}

extern "C" void kernel_launch(void* const* d_in, const int* in_sizes, int n_in,
                              void* d_out, int out_size, void* d_ws, size_t ws_size,
                              hipStream_t stream) {
    const float* x  = (const float*)d_in[0];
    const float* wk = (const float*)d_in[1];
    const float* bk = (const float*)d_in[2];
    const float* wv = (const float*)d_in[3];
    const float* bv = (const float*)d_in[4];
    const float* wo = (const float*)d_in[5];
    const float* bo = (const float*)d_in[6];
    float* o = (float*)d_out;
    psab_fused<<<dim3(512), dim3(512), 0, stream>>>(x, wk, bk, wv, bv, wo, bo, o);
}

// Round 9
// 76.048 us; speedup vs baseline: 5.9777x; 5.9777x over previous
//
#include <hip/hip_runtime.h>

typedef unsigned short u16;
typedef __bf16 bf16x8 __attribute__((ext_vector_type(8)));
typedef float f32x16 __attribute__((ext_vector_type(16)));

union B8 { bf16x8 v; u16 s[8]; unsigned u[4]; uint4 u4; };

__device__ __forceinline__ unsigned cvtpk(float a, float b) {
    unsigned r;
    asm("v_cvt_pk_bf16_f32 %0, %1, %2" : "=v"(r) : "v"(a), "v"(b));
    return r;
}
__device__ __forceinline__ float ex2(float x) { return __builtin_amdgcn_exp2f(x); }
// VALU-only exp2 (cubic, rel err <= ~3e-4): balances the trans pipe
__device__ __forceinline__ float ex2p(float x) {
    float n = floorf(x);
    float f = x - n;
    float p = fmaf(f, 0.0802449f, 0.224368f);
    p = fmaf(f, p, 0.695348f);
    p = fmaf(f, p, 1.0f);
    int e = ((int)n + 127) << 23;
    return __int_as_float(e) * p;
}
__device__ __forceinline__ void swap32(unsigned &a, unsigned &b) {
    asm("v_permlane32_swap_b32 %0, %1" : "+v"(a), "+v"(b));
}
__device__ __forceinline__ B8 load_w8(const float* __restrict__ p, float s) {
    float4 lo = ((const float4*)p)[0];
    float4 hi = ((const float4*)p)[1];
    B8 r;
    r.u[0] = cvtpk(lo.x * s, lo.y * s);
    r.u[1] = cvtpk(lo.z * s, lo.w * s);
    r.u[2] = cvtpk(hi.x * s, hi.y * s);
    r.u[3] = cvtpk(hi.z * s, hi.w * s);
    return r;
}
__device__ __forceinline__ f32x16 mfma32(const B8 a, const B8 b, f32x16 c) {
    return __builtin_amdgcn_mfma_f32_32x32x16_bf16(a.v, b.v, c, 0, 0, 0);
}
// K LDS: [512 tok][32 ck] u16, 4x16B slots per row XOR-swizzled by (tok>>1)&3
__device__ __forceinline__ int kidx(int row, int sl) {
    return row * 32 + (((sl ^ (row >> 1)) & 3) << 3);
}
// D-regs (rows (r&3)+8*(r>>2)+4*h5) -> two B-fragments (k-chunks of 16) via cvtpk+permlane
__device__ __forceinline__ void build_b(const float* p, B8& b0, B8& b1) {
    unsigned c0 = cvtpk(p[0], p[1]),   c1 = cvtpk(p[2], p[3]);
    unsigned c2 = cvtpk(p[4], p[5]),   c3 = cvtpk(p[6], p[7]);
    unsigned c4 = cvtpk(p[8], p[9]),   c5 = cvtpk(p[10], p[11]);
    unsigned c6 = cvtpk(p[12], p[13]), c7 = cvtpk(p[14], p[15]);
    swap32(c0, c2); swap32(c1, c3); swap32(c4, c6); swap32(c5, c7);
    b0.u[0] = c0; b0.u[1] = c1; b0.u[2] = c2; b0.u[3] = c3;
    b1.u[0] = c4; b1.u[1] = c5; b1.u[2] = c6; b1.u[3] = c7;
}

// LDS (u16 idx): K [512][32] @0 (32768B) | V [64][520] @16384 (66560B) | X [256][72] @49664 (36864B)
// epilogue: 8 wave-slots of 16KB f32 fout overlay @byte 0
#define VOFF 16384
#define XOFF 49664
#define NSM  68096

__global__ __launch_bounds__(512, 1)
void psab_fused(const float* __restrict__ x,
                const float* __restrict__ wk, const float* __restrict__ bk,
                const float* __restrict__ wv, const float* __restrict__ bv,
                const float* __restrict__ wo, const float* __restrict__ bo,
                float* __restrict__ out)
{
    __shared__ __align__(16) u16 smem[NSM];
    const int t    = threadIdx.x;
    const int lane = t & 63;
    const int wid  = t >> 6;       // wave = hb row of the window
    const int cl   = lane & 31;
    const int h5   = lane >> 5;

    const int bid = blockIdx.x;
    const int n   = (bid & 7) * 64 + (bid >> 3);   // XCD-bijective swizzle
    const int sh = n >> 6, sw = (n >> 3) & 7, sd = n & 7;
    const size_t base_vox = (size_t)(sh * 8) * 4096 + (size_t)(sw * 8) * 64 + (size_t)(sd * 8);

    const float WSC = 0.50506330f;   // sqrt(log2(e)/sqrt(32)) folded into K weights

    B8 wkA[4], wvB[2][4];
#pragma unroll
    for (int kc = 0; kc < 4; ++kc)
        wkA[kc] = load_w8(wk + cl * 64 + kc * 16 + h5 * 8, WSC);
#pragma unroll
    for (int nb = 0; nb < 2; ++nb)
#pragma unroll
        for (int kc = 0; kc < 4; ++kc)
            wvB[nb][kc] = load_w8(wv + (nb * 32 + cl) * 64 + kc * 16 + h5 * 8, 1.0f);
    float bkv[16];
#pragma unroll
    for (int r = 0; r < 16; ++r)
        bkv[r] = bk[(r & 3) + 8 * (r >> 2) + 4 * h5] * WSC;
    const float vbias[2] = { bv[cl], bv[32 + cl] };

    const f32x16 z16 = {0,0,0,0,0,0,0,0,0,0,0,0,0,0,0,0};

    // ---- X staging: 2 chunks x 256 tok (4 hb x 8 wb x 8 db); thread (cS,r2) ----
    const int cS = t & 63;
    const int r2 = t >> 6;
    float4 L4[4], H4[4];
#define LDX(cc)                                                                              \
    _Pragma("unroll")                                                                        \
    for (int i = 0; i < 4; ++i) {                                                            \
        const float* gp = x + (size_t)cS * 262144 + base_vox + ((cc) * 4 + i) * 4096 + r2 * 64; \
        L4[i] = ((const float4*)gp)[0];                                                      \
        H4[i] = ((const float4*)gp)[1];                                                      \
    }
#define STX()                                                                                \
    _Pragma("unroll")                                                                        \
    for (int i = 0; i < 4; ++i) {                                                            \
        unsigned a0 = cvtpk(L4[i].x, L4[i].y), a1 = cvtpk(L4[i].z, L4[i].w);                 \
        unsigned a2 = cvtpk(H4[i].x, H4[i].y), a3 = cvtpk(H4[i].z, H4[i].w);                 \
        u16* xp = &smem[XOFF + (i * 64 + r2 * 8) * 72 + cS];                                 \
        xp[0 * 72] = (u16)a0; xp[1 * 72] = (u16)(a0 >> 16);                                  \
        xp[2 * 72] = (u16)a1; xp[3 * 72] = (u16)(a1 >> 16);                                  \
        xp[4 * 72] = (u16)a2; xp[5 * 72] = (u16)(a2 >> 16);                                  \
        xp[6 * 72] = (u16)a3; xp[7 * 72] = (u16)(a3 >> 16);                                  \
    }

    LDX(0)
    STX()
    __syncthreads();                          // (1) X0 visible
    LDX(1)                                    // prefetch chunk1 under proj-chunk0 compute

#pragma unroll
    for (int cc = 0; cc < 2; ++cc) {
        const int tokb = cc * 256 + wid * 32;
        B8 ax[4];
#pragma unroll
        for (int kc = 0; kc < 4; ++kc)
            ax[kc].u4 = *(const uint4*)&smem[XOFF + (wid * 32 + cl) * 72 + kc * 16 + h5 * 8];
        // K proj, swapped operands: D col = tok = cl, rows = ck -> 4 packed uint2 stores
        f32x16 kd = mfma32(wkA[0], ax[0], z16);
        kd = mfma32(wkA[1], ax[1], kd);
        kd = mfma32(wkA[2], ax[2], kd);
        kd = mfma32(wkA[3], ax[3], kd);
        const int trow = tokb + cl;
#pragma unroll
        for (int g = 0; g < 4; ++g) {
            uint2 pk;
            pk.x = cvtpk(kd[4 * g + 0] + bkv[4 * g + 0], kd[4 * g + 1] + bkv[4 * g + 1]);
            pk.y = cvtpk(kd[4 * g + 2] + bkv[4 * g + 2], kd[4 * g + 3] + bkv[4 * g + 3]);
            *(uint2*)&smem[kidx(trow, g) + 4 * h5] = pk;
        }
        // V proj: D col = cv, rows = tok -> V^T[cv][tok] packed uint2
#pragma unroll
        for (int nb = 0; nb < 2; ++nb) {
            f32x16 vd = mfma32(ax[0], wvB[nb][0], z16);
            vd = mfma32(ax[1], wvB[nb][1], vd);
            vd = mfma32(ax[2], wvB[nb][2], vd);
            vd = mfma32(ax[3], wvB[nb][3], vd);
            const int cv = nb * 32 + cl;
            const float vb = vbias[nb];
#pragma unroll
            for (int rq = 0; rq < 4; ++rq) {
                uint2 pk;
                pk.x = cvtpk(vd[rq * 4 + 0] + vb, vd[rq * 4 + 1] + vb);
                pk.y = cvtpk(vd[rq * 4 + 2] + vb, vd[rq * 4 + 3] + vb);
                *(uint2*)&smem[VOFF + cv * 520 + tokb + rq * 8 + 4 * h5] = pk;
            }
        }
        if (cc == 0) {
            __syncthreads();                  // (2) X0 readers done
            STX()
            __syncthreads();                  // (3) X1 visible
        }
    }
    __syncthreads();                          // (4) K/V complete

    // ---- attention: wave owns q = wid*64 + qb*32 + cl; m in 16 chunks of 32 ----
    B8 qB[2][2];
#pragma unroll
    for (int qb = 0; qb < 2; ++qb)
#pragma unroll
        for (int kc = 0; kc < 2; ++kc)
            qB[qb][kc].u4 = *(const uint4*)&smem[kidx(wid * 64 + qb * 32 + cl, 2 * kc + h5)];

    B8 ones;
    ones.u[0] = 0x3f803f80u; ones.u[1] = 0x3f803f80u;
    ones.u[2] = 0x3f803f80u; ones.u[3] = 0x3f803f80u;

    f32x16 ctx00 = z16, ctx01 = z16, ctx10 = z16, ctx11 = z16;  // ctx[qb][cvb]
    f32x16 lacc0 = z16, lacc1 = z16;                            // lsum via ones-MFMA

    // hybrid exp: 13 via trans pipe, 3 via VALU poly (pipes balanced)
#define SM(sv, lac, c0, c1)                                                                   \
    {                                                                                         \
        float p[16];                                                                          \
        _Pragma("unroll")                                                                     \
        for (int i2 = 0; i2 < 13; ++i2) p[i2] = ex2(sv[i2]);                                  \
        p[13] = ex2p(sv[13]); p[14] = ex2p(sv[14]); p[15] = ex2p(sv[15]);                     \
        B8 pb0, pb1;                                                                          \
        build_b(p, pb0, pb1);                                                                 \
        __builtin_amdgcn_s_setprio(1);                                                        \
        lac = mfma32(ones, pb0, lac);                                                         \
        lac = mfma32(ones, pb1, lac);                                                         \
        c0 = mfma32(va00, pb0, c0);                                                           \
        c0 = mfma32(va01, pb1, c0);                                                           \
        c1 = mfma32(va10, pb0, c1);                                                           \
        c1 = mfma32(va11, pb1, c1);                                                           \
        __builtin_amdgcn_s_setprio(0);                                                        \
    }

#pragma unroll 1
    for (int ci = 0; ci < 16; ++ci) {
        const int m0 = ci * 32;
        B8 kA0, kA1, va00, va01, va10, va11;
        kA0.u4  = *(const uint4*)&smem[kidx(m0 + cl, h5)];
        kA1.u4  = *(const uint4*)&smem[kidx(m0 + cl, 2 + h5)];
        va00.u4 = *(const uint4*)&smem[VOFF + cl * 520 + m0 + h5 * 8];
        va01.u4 = *(const uint4*)&smem[VOFF + cl * 520 + m0 + 16 + h5 * 8];
        va10.u4 = *(const uint4*)&smem[VOFF + (32 + cl) * 520 + m0 + h5 * 8];
        va11.u4 = *(const uint4*)&smem[VOFF + (32 + cl) * 520 + m0 + 16 + h5 * 8];

        __builtin_amdgcn_s_setprio(1);
        f32x16 s0 = mfma32(kA0, qB[0][0], z16); s0 = mfma32(kA1, qB[0][1], s0);
        f32x16 s1 = mfma32(kA0, qB[1][0], z16); s1 = mfma32(kA1, qB[1][1], s1);
        __builtin_amdgcn_s_setprio(0);

        SM(s0, lacc0, ctx00, ctx01)
        SM(s1, lacc1, ctx10, ctx11)
    }

    const float inv0 = 1.0f / lacc0[0];   // every reg/lane of lacc holds the full row-sum for its q
    const float inv1 = 1.0f / lacc1[0];

    // out-proj A-frags (wo) + ctx -> B-frags in registers
    B8 aw[2][4];
#pragma unroll
    for (int cob = 0; cob < 2; ++cob)
#pragma unroll
        for (int kc = 0; kc < 4; ++kc)
            aw[cob][kc] = load_w8(wo + (cob * 32 + cl) * 64 + kc * 16 + h5 * 8, 1.0f);

    float pn[16];
    B8 cq0[4], cq1[4];   // B-frags per qb over k=cv chunks 0..3
#pragma unroll
    for (int i = 0; i < 16; ++i) pn[i] = ctx00[i] * inv0;
    build_b(pn, cq0[0], cq0[1]);
#pragma unroll
    for (int i = 0; i < 16; ++i) pn[i] = ctx01[i] * inv0;
    build_b(pn, cq0[2], cq0[3]);
#pragma unroll
    for (int i = 0; i < 16; ++i) pn[i] = ctx10[i] * inv1;
    build_b(pn, cq1[0], cq1[1]);
#pragma unroll
    for (int i = 0; i < 16; ++i) pn[i] = ctx11[i] * inv1;
    build_b(pn, cq1[2], cq1[3]);

    __syncthreads();                          // (5) K/V readers done; LDS -> fout slots

    float* fout = (float*)((char*)smem + wid * 16384);   // [64 co][64 q] f32
#pragma unroll
    for (int cob = 0; cob < 2; ++cob) {
        f32x16 od0 = mfma32(aw[cob][0], cq0[0], z16);
        od0 = mfma32(aw[cob][1], cq0[1], od0);
        od0 = mfma32(aw[cob][2], cq0[2], od0);
        od0 = mfma32(aw[cob][3], cq0[3], od0);
        f32x16 od1 = mfma32(aw[cob][0], cq1[0], z16);
        od1 = mfma32(aw[cob][1], cq1[1], od1);
        od1 = mfma32(aw[cob][2], cq1[2], od1);
        od1 = mfma32(aw[cob][3], cq1[3], od1);
#pragma unroll
        for (int r = 0; r < 16; ++r) {
            const int row = cob * 32 + (r & 3) + 8 * (r >> 2) + 4 * h5;
            fout[row * 64 + cl]      = od0[r];
            fout[row * 64 + 32 + cl] = od1[r];
        }
    }

    // coalesced global store: wave = hb row; q = wb*8+db (bias added here)
    float* outw = out + base_vox + (size_t)wid * 4096;
    const int lq = lane >> 4, lr = lane & 15;
#pragma unroll
    for (int it = 0; it < 16; ++it) {
        const int co = it * 4 + lq;
        float4 v4 = *(const float4*)&fout[co * 64 + lr * 4];
        const float bco = bo[co];
        v4.x += bco; v4.y += bco; v4.z += bco; v4.w += bco;
        const int wb = lr >> 1, db0 = (lr & 1) * 4;
        *(float4*)&outw[(size_t)co * 262144 + wb * 64 + db0] = v4;
    }
}

extern "C" void kernel_launch(void* const* d_in, const int* in_sizes, int n_in,
                              void* d_out, int out_size, void* d_ws, size_t ws_size,
                              hipStream_t stream) {
    const float* x  = (const float*)d_in[0];
    const float* wk = (const float*)d_in[1];
    const float* bk = (const float*)d_in[2];
    const float* wv = (const float*)d_in[3];
    const float* bv = (const float*)d_in[4];
    const float* wo = (const float*)d_in[5];
    const float* bo = (const float*)d_in[6];
    float* o = (float*)d_out;
    psab_fused<<<dim3(512), dim3(512), 0, stream>>>(x, wk, bk, wv, bv, wo, bo, o);
}

// Round 10
// 68.885 us; speedup vs baseline: 6.5992x; 1.1040x over previous
//
#include <hip/hip_runtime.h>

typedef unsigned short u16;
typedef __bf16 bf16x8 __attribute__((ext_vector_type(8)));
typedef float f32x16 __attribute__((ext_vector_type(16)));

union B8 { bf16x8 v; u16 s[8]; unsigned u[4]; uint4 u4; };

__device__ __forceinline__ unsigned cvtpk(float a, float b) {
    unsigned r;
    asm("v_cvt_pk_bf16_f32 %0, %1, %2" : "=v"(r) : "v"(a), "v"(b));
    return r;
}
__device__ __forceinline__ float ex2(float x) { return __builtin_amdgcn_exp2f(x); }
__device__ __forceinline__ void swap32(unsigned &a, unsigned &b) {
    asm("v_permlane32_swap_b32 %0, %1" : "+v"(a), "+v"(b));
}
__device__ __forceinline__ B8 load_w8(const float* __restrict__ p, float s) {
    float4 lo = ((const float4*)p)[0];
    float4 hi = ((const float4*)p)[1];
    B8 r;
    r.u[0] = cvtpk(lo.x * s, lo.y * s);
    r.u[1] = cvtpk(lo.z * s, lo.w * s);
    r.u[2] = cvtpk(hi.x * s, hi.y * s);
    r.u[3] = cvtpk(hi.z * s, hi.w * s);
    return r;
}
__device__ __forceinline__ f32x16 mfma32(const B8 a, const B8 b, f32x16 c) {
    return __builtin_amdgcn_mfma_f32_32x32x16_bf16(a.v, b.v, c, 0, 0, 0);
}
// K LDS: [512 tok][32 ck] u16, 4x16B slots per row XOR-swizzled by (tok>>1)&3
__device__ __forceinline__ int kidx(int row, int sl) {
    return row * 32 + (((sl ^ (row >> 1)) & 3) << 3);
}
// D-regs (rows (r&3)+8*(r>>2)+4*h5) -> two B-fragments (k-chunks of 16) via cvtpk+permlane
__device__ __forceinline__ void build_b(const float* p, B8& b0, B8& b1) {
    unsigned c0 = cvtpk(p[0], p[1]),   c1 = cvtpk(p[2], p[3]);
    unsigned c2 = cvtpk(p[4], p[5]),   c3 = cvtpk(p[6], p[7]);
    unsigned c4 = cvtpk(p[8], p[9]),   c5 = cvtpk(p[10], p[11]);
    unsigned c6 = cvtpk(p[12], p[13]), c7 = cvtpk(p[14], p[15]);
    swap32(c0, c2); swap32(c1, c3); swap32(c4, c6); swap32(c5, c7);
    b0.u[0] = c0; b0.u[1] = c1; b0.u[2] = c2; b0.u[3] = c3;
    b1.u[0] = c4; b1.u[1] = c5; b1.u[2] = c6; b1.u[3] = c7;
}

// LDS (u16 idx): K [512][32] @0 (32768B) | V [64][520] @16384 (66560B) | X [256][72] @49664 (36864B)
#define VOFF 16384
#define XOFF 49664
#define NSM  68096

__global__ __launch_bounds__(512, 1)
void psab_fused(const float* __restrict__ x,
                const float* __restrict__ wk, const float* __restrict__ bk,
                const float* __restrict__ wv, const float* __restrict__ bv,
                const float* __restrict__ wo, const float* __restrict__ bo,
                float* __restrict__ out)
{
    __shared__ __align__(16) u16 smem[NSM];
    const int t    = threadIdx.x;
    const int lane = t & 63;
    const int wid  = t >> 6;       // wave = hb row of the window
    const int cl   = lane & 31;
    const int h5   = lane >> 5;

    const int bid = blockIdx.x;
    const int n   = (bid & 7) * 64 + (bid >> 3);   // XCD-bijective swizzle
    const int sh = n >> 6, sw = (n >> 3) & 7, sd = n & 7;
    const size_t base_vox = (size_t)(sh * 8) * 4096 + (size_t)(sw * 8) * 64 + (size_t)(sd * 8);

    const float WSC = 0.50506330f;   // sqrt(log2(e)/sqrt(32)) folded into K weights

    B8 wkA[4], wvB[2][4];
#pragma unroll
    for (int kc = 0; kc < 4; ++kc)
        wkA[kc] = load_w8(wk + cl * 64 + kc * 16 + h5 * 8, WSC);
#pragma unroll
    for (int nb = 0; nb < 2; ++nb)
#pragma unroll
        for (int kc = 0; kc < 4; ++kc)
            wvB[nb][kc] = load_w8(wv + (nb * 32 + cl) * 64 + kc * 16 + h5 * 8, 1.0f);
    float bkv[16];
#pragma unroll
    for (int r = 0; r < 16; ++r)
        bkv[r] = bk[(r & 3) + 8 * (r >> 2) + 4 * h5] * WSC;
    const float vbias[2] = { bv[cl], bv[32 + cl] };

    const f32x16 z16 = {0,0,0,0,0,0,0,0,0,0,0,0,0,0,0,0};

    // ---- X staging: 2 chunks x 256 tok (4 hb x 8 wb x 8 db); thread (cS,r2) ----
    const int cS = t & 63;
    const int r2 = t >> 6;
    float4 L4[4], H4[4];
#define LDX(cc)                                                                              \
    _Pragma("unroll")                                                                        \
    for (int i = 0; i < 4; ++i) {                                                            \
        const float* gp = x + (size_t)cS * 262144 + base_vox + ((cc) * 4 + i) * 4096 + r2 * 64; \
        L4[i] = ((const float4*)gp)[0];                                                      \
        H4[i] = ((const float4*)gp)[1];                                                      \
    }
#define STX()                                                                                \
    _Pragma("unroll")                                                                        \
    for (int i = 0; i < 4; ++i) {                                                            \
        unsigned a0 = cvtpk(L4[i].x, L4[i].y), a1 = cvtpk(L4[i].z, L4[i].w);                 \
        unsigned a2 = cvtpk(H4[i].x, H4[i].y), a3 = cvtpk(H4[i].z, H4[i].w);                 \
        u16* xp = &smem[XOFF + (i * 64 + r2 * 8) * 72 + cS];                                 \
        xp[0 * 72] = (u16)a0; xp[1 * 72] = (u16)(a0 >> 16);                                  \
        xp[2 * 72] = (u16)a1; xp[3 * 72] = (u16)(a1 >> 16);                                  \
        xp[4 * 72] = (u16)a2; xp[5 * 72] = (u16)(a2 >> 16);                                  \
        xp[6 * 72] = (u16)a3; xp[7 * 72] = (u16)(a3 >> 16);                                  \
    }

    LDX(0)
    STX()
    __syncthreads();                          // (1) X0 visible
    LDX(1)                                    // prefetch chunk1 under proj-chunk0 compute

#pragma unroll
    for (int cc = 0; cc < 2; ++cc) {
        const int tokb = cc * 256 + wid * 32;
        B8 ax[4];
#pragma unroll
        for (int kc = 0; kc < 4; ++kc)
            ax[kc].u4 = *(const uint4*)&smem[XOFF + (wid * 32 + cl) * 72 + kc * 16 + h5 * 8];
        // K proj, swapped operands: D col = tok = cl, rows = ck -> 4 packed uint2 stores
        f32x16 kd = mfma32(wkA[0], ax[0], z16);
        kd = mfma32(wkA[1], ax[1], kd);
        kd = mfma32(wkA[2], ax[2], kd);
        kd = mfma32(wkA[3], ax[3], kd);
        const int trow = tokb + cl;
#pragma unroll
        for (int g = 0; g < 4; ++g) {
            uint2 pk;
            pk.x = cvtpk(kd[4 * g + 0] + bkv[4 * g + 0], kd[4 * g + 1] + bkv[4 * g + 1]);
            pk.y = cvtpk(kd[4 * g + 2] + bkv[4 * g + 2], kd[4 * g + 3] + bkv[4 * g + 3]);
            *(uint2*)&smem[kidx(trow, g) + 4 * h5] = pk;
        }
        // V proj: D col = cv, rows = tok -> V^T[cv][tok] packed uint2
#pragma unroll
        for (int nb = 0; nb < 2; ++nb) {
            f32x16 vd = mfma32(ax[0], wvB[nb][0], z16);
            vd = mfma32(ax[1], wvB[nb][1], vd);
            vd = mfma32(ax[2], wvB[nb][2], vd);
            vd = mfma32(ax[3], wvB[nb][3], vd);
            const int cv = nb * 32 + cl;
            const float vb = vbias[nb];
#pragma unroll
            for (int rq = 0; rq < 4; ++rq) {
                uint2 pk;
                pk.x = cvtpk(vd[rq * 4 + 0] + vb, vd[rq * 4 + 1] + vb);
                pk.y = cvtpk(vd[rq * 4 + 2] + vb, vd[rq * 4 + 3] + vb);
                *(uint2*)&smem[VOFF + cv * 520 + tokb + rq * 8 + 4 * h5] = pk;
            }
        }
        if (cc == 0) {
            __syncthreads();                  // (2) X0 readers done
            STX()
            __syncthreads();                  // (3) X1 visible
        }
    }
    __syncthreads();                          // (4) K/V complete

    // ---- attention: wave owns q = wid*64 + qb*32 + cl; explicit 2-stage reg pipeline ----
    B8 qB[2][2];
#pragma unroll
    for (int qb = 0; qb < 2; ++qb)
#pragma unroll
        for (int kc = 0; kc < 2; ++kc)
            qB[qb][kc].u4 = *(const uint4*)&smem[kidx(wid * 64 + qb * 32 + cl, 2 * kc + h5)];

    B8 ones;
    ones.u[0] = 0x3f803f80u; ones.u[1] = 0x3f803f80u;
    ones.u[2] = 0x3f803f80u; ones.u[3] = 0x3f803f80u;

    f32x16 ctx00 = z16, ctx01 = z16, ctx10 = z16, ctx11 = z16;  // ctx[qb][cvb]
    f32x16 lacc0 = z16, lacc1 = z16;                            // row-sum via ones-MFMA

#define LOADF(P, M0)                                                                          \
    P##k0.u4  = *(const uint4*)&smem[kidx((M0) + cl, h5)];                                    \
    P##k1.u4  = *(const uint4*)&smem[kidx((M0) + cl, 2 + h5)];                                \
    P##v00.u4 = *(const uint4*)&smem[VOFF + cl * 520 + (M0) + h5 * 8];                        \
    P##v01.u4 = *(const uint4*)&smem[VOFF + cl * 520 + (M0) + 16 + h5 * 8];                   \
    P##v10.u4 = *(const uint4*)&smem[VOFF + (32 + cl) * 520 + (M0) + h5 * 8];                 \
    P##v11.u4 = *(const uint4*)&smem[VOFF + (32 + cl) * 520 + (M0) + 16 + h5 * 8];

#define SM(sv, lac, c0, c1, P)                                                                \
    {                                                                                         \
        float p[16];                                                                          \
        _Pragma("unroll")                                                                     \
        for (int i2 = 0; i2 < 16; ++i2) p[i2] = ex2(sv[i2]);                                  \
        B8 pb0, pb1;                                                                          \
        build_b(p, pb0, pb1);                                                                 \
        lac = mfma32(ones, pb0, lac);                                                         \
        lac = mfma32(ones, pb1, lac);                                                         \
        c0 = mfma32(P##v00, pb0, c0);                                                         \
        c0 = mfma32(P##v01, pb1, c0);                                                         \
        c1 = mfma32(P##v10, pb0, c1);                                                         \
        c1 = mfma32(P##v11, pb1, c1);                                                         \
    }

#define COMPUTE(P)                                                                            \
    {                                                                                         \
        f32x16 s0 = mfma32(P##k0, qB[0][0], z16); s0 = mfma32(P##k1, qB[0][1], s0);           \
        f32x16 s1 = mfma32(P##k0, qB[1][0], z16); s1 = mfma32(P##k1, qB[1][1], s1);           \
        SM(s0, lacc0, ctx00, ctx01, P)                                                        \
        SM(s1, lacc1, ctx10, ctx11, P)                                                        \
    }

    B8 fAk0, fAk1, fAv00, fAv01, fAv10, fAv11;
    B8 fBk0, fBk1, fBv00, fBv01, fBv10, fBv11;
    LOADF(fA, 0)
#pragma unroll 1
    for (int cp = 0; cp < 8; ++cp) {
        const int m1 = cp * 64 + 32;
        LOADF(fB, m1)                          // issue next frags before computing current
        COMPUTE(fA)
        if (cp < 7) {
            const int m2 = cp * 64 + 64;
            LOADF(fA, m2)
        }
        COMPUTE(fB)
    }

    const float inv0 = 1.0f / lacc0[0];
    const float inv1 = 1.0f / lacc1[0];

    // out-proj A-frags + ctx -> B-frags (registers only)
    B8 aw[2][4];
#pragma unroll
    for (int cob = 0; cob < 2; ++cob)
#pragma unroll
        for (int kc = 0; kc < 4; ++kc)
            aw[cob][kc] = load_w8(wo + (cob * 32 + cl) * 64 + kc * 16 + h5 * 8, 1.0f);

    float pn[16];
    B8 cq0[4], cq1[4];   // B-frags per qb over k=cv chunks 0..3
#pragma unroll
    for (int i = 0; i < 16; ++i) pn[i] = ctx00[i] * inv0;
    build_b(pn, cq0[0], cq0[1]);
#pragma unroll
    for (int i = 0; i < 16; ++i) pn[i] = ctx01[i] * inv0;
    build_b(pn, cq0[2], cq0[3]);
#pragma unroll
    for (int i = 0; i < 16; ++i) pn[i] = ctx10[i] * inv1;
    build_b(pn, cq1[0], cq1[1]);
#pragma unroll
    for (int i = 0; i < 16; ++i) pn[i] = ctx11[i] * inv1;
    build_b(pn, cq1[2], cq1[3]);

    // bias as rank-1 MFMA: A = splat(bo[co-row]), B = splat(bf16(1/16)); sum_k = bo
    B8 abo[2], ones16;
    {
        unsigned b0 = cvtpk(bo[cl], bo[cl]);
        unsigned b1 = cvtpk(bo[32 + cl], bo[32 + cl]);
        abo[0].u[0] = b0; abo[0].u[1] = b0; abo[0].u[2] = b0; abo[0].u[3] = b0;
        abo[1].u[0] = b1; abo[1].u[1] = b1; abo[1].u[2] = b1; abo[1].u[3] = b1;
        ones16.u[0] = 0x3d803d80u; ones16.u[1] = 0x3d803d80u;
        ones16.u[2] = 0x3d803d80u; ones16.u[3] = 0x3d803d80u;
    }

    // ---- direct global stores from accumulators (no LDS round-trip, no barrier) ----
    float* ob = out + base_vox;
    const int voxb = wid * 4096 + (cl >> 3) * 64 + (cl & 7) + h5 * 1048576;   // qb=0; qb=1 -> +256
#pragma unroll
    for (int cob = 0; cob < 2; ++cob) {
        f32x16 od0 = mfma32(aw[cob][0], cq0[0], z16);
        od0 = mfma32(aw[cob][1], cq0[1], od0);
        od0 = mfma32(aw[cob][2], cq0[2], od0);
        od0 = mfma32(aw[cob][3], cq0[3], od0);
        od0 = mfma32(abo[cob], ones16, od0);
        f32x16 od1 = mfma32(aw[cob][0], cq1[0], z16);
        od1 = mfma32(aw[cob][1], cq1[1], od1);
        od1 = mfma32(aw[cob][2], cq1[2], od1);
        od1 = mfma32(aw[cob][3], cq1[3], od1);
        od1 = mfma32(abo[cob], ones16, od1);
#pragma unroll
        for (int r = 0; r < 16; ++r) {
            const int cop = cob * 32 + (r & 3) + 8 * (r >> 2);   // + 4*h5 via voxb
            ob[(size_t)cop * 262144 + voxb]       = od0[r];
            ob[(size_t)cop * 262144 + voxb + 256] = od1[r];
        }
    }
}

extern "C" void kernel_launch(void* const* d_in, const int* in_sizes, int n_in,
                              void* d_out, int out_size, void* d_ws, size_t ws_size,
                              hipStream_t stream) {
    const float* x  = (const float*)d_in[0];
    const float* wk = (const float*)d_in[1];
    const float* bk = (const float*)d_in[2];
    const float* wv = (const float*)d_in[3];
    const float* bv = (const float*)d_in[4];
    const float* wo = (const float*)d_in[5];
    const float* bo = (const float*)d_in[6];
    float* o = (float*)d_out;
    psab_fused<<<dim3(512), dim3(512), 0, stream>>>(x, wk, bk, wv, bv, wo, bo, o);
}